// Round 4
// baseline (797.546 us; speedup 1.0000x reference)
//
#include <hip/hip_runtime.h>
#include <hip/hip_bf16.h>
#include <math.h>

typedef __bf16 bf16_t;
typedef bf16_t bf16x8 __attribute__((ext_vector_type(8)));
typedef bf16_t bf16x4 __attribute__((ext_vector_type(4)));
typedef bf16_t bf16x2 __attribute__((ext_vector_type(2)));
typedef float f32x4 __attribute__((ext_vector_type(4)));

#define D_MODEL 1024
#define SEQ     4096
#define BATCH   4
#define NTOK    16384   // BATCH*SEQ
#define DFF     4096
#define CLEN    64      // scan chunk length
#define NCHUNK  64      // chunks per sequence (CLEN*NCHUNK == SEQ)
#define NCH     4096    // channels = BATCH*D_MODEL

// async global->LDS, 16B per lane; LDS dest is wave-uniform base + lane*16
__device__ __forceinline__ void gload16(const bf16_t* g, bf16_t* l) {
    __builtin_amdgcn_global_load_lds(
        (const __attribute__((address_space(1))) void*)g,
        (__attribute__((address_space(3))) void*)l, 16, 0, 0);
}

// ---------------------------------------------------------------------------
// Transpose fp32 [R][C] -> bf16 [C][R]
// ---------------------------------------------------------------------------
__global__ void transpose_to_bf16(const float* __restrict__ W,
                                  bf16_t* __restrict__ Wt, int R, int C) {
    __shared__ float tile[32][33];
    const int c0 = blockIdx.x * 32, r0 = blockIdx.y * 32;
    const int tx = threadIdx.x, ty = threadIdx.y;
#pragma unroll
    for (int j = 0; j < 32; j += 8)
        tile[ty + j][tx] = W[(size_t)(r0 + ty + j) * C + c0 + tx];
    __syncthreads();
#pragma unroll
    for (int j = 0; j < 32; j += 8)
        Wt[(size_t)(c0 + ty + j) * R + r0 + tx] = (bf16_t)tile[tx][ty + j];
}

// ---------------------------------------------------------------------------
// RMSNorm: fp32 [rows][1024] -> bf16 [rows][1024]   (block = 256 thr per row)
// ---------------------------------------------------------------------------
__global__ void rmsnorm_kernel(const float* __restrict__ x,
                               const float* __restrict__ w,
                               bf16_t* __restrict__ out) {
    const int row = blockIdx.x;
    const int tid = threadIdx.x;
    const float4 v = ((const float4*)(x + (size_t)row * D_MODEL))[tid];
    float ss = v.x * v.x + v.y * v.y + v.z * v.z + v.w * v.w;
#pragma unroll
    for (int o = 1; o < 64; o <<= 1) ss += __shfl_xor(ss, o);
    __shared__ float red[4];
    if ((tid & 63) == 0) red[tid >> 6] = ss;
    __syncthreads();
    const float tot = red[0] + red[1] + red[2] + red[3];
    const float scale = rsqrtf(tot * (1.0f / D_MODEL) + 1e-6f);
    const float4 wv = ((const float4*)w)[tid];
    bf16x4 o4;
    o4[0] = (bf16_t)(v.x * scale * wv.x);
    o4[1] = (bf16_t)(v.y * scale * wv.y);
    o4[2] = (bf16_t)(v.z * scale * wv.z);
    o4[3] = (bf16_t)(v.w * scale * wv.w);
    ((bf16x4*)(out + (size_t)row * D_MODEL))[tid] = o4;
}

// ---------------------------------------------------------------------------
// 256-row GEMM, BK=64, 512 threads = 8 waves (2M x 4N), double-buffered LDS,
// ONE __syncthreads per K-tile, fragment ds_reads software-pipelined one
// phase ahead (register double-buffer), compiler-managed lgkmcnt.
//   MODE 0: dual-B BN=128, GC = {sigmoid(A@B1+b1), tanh(A@B2+b2)} bf16x2
//   MODE 1: dual-B BN=128, Ot = silu(A@B1) * (A@B2)   (bf16)
//   MODE 2: single-B BN=256, O += A@B                  (fp32, in-place)
// A: bf16 [M][K]; B*t: bf16 [N][K]. K % 64 == 0, grid % 8 == 0.
// LDS per buffer (32768 bf16): A 256x64 @0; B dual: 128x64 @16384 + 128x64
// @24576; single: 256x64 @16384. Swizzle: 16B chunk c of row r at slot
// c^(r&7); staged via pre-swizzled per-lane GLOBAL address, linear LDS dest.
// ---------------------------------------------------------------------------
#define MFMA16(a, b, c) __builtin_amdgcn_mfma_f32_16x16x32_bf16((a), (b), (c), 0, 0, 0)

template <int MODE>
__global__ __launch_bounds__(512, 2)
void gemm8p(const bf16_t* __restrict__ A, const bf16_t* __restrict__ B1t,
            const bf16_t* __restrict__ B2t, const float* __restrict__ bias1,
            const float* __restrict__ bias2, bf16x2* __restrict__ GC,
            bf16_t* __restrict__ Ot, float* __restrict__ O,
            int N, int K, int lg_nbn) {
    constexpr bool DUAL = (MODE != 2);
    constexpr int BN = DUAL ? 128 : 256;
    constexpr int NFR = DUAL ? 2 : 4;     // n-fragments per wave
    constexpr int NMAT = DUAL ? 2 : 1;
    __shared__ bf16_t lds[65536];         // 128 KiB

    const int tid = threadIdx.x;
    const int lane = tid & 63;
    const int wave = tid >> 6;            // 0..7
    const int wr = wave >> 2, wc = wave & 3;
    const int lr16 = lane & 15, lk = lane >> 4;

    // XCD-bijective block swizzle (gridDim.x % 8 == 0 for all our launches)
    const int nwg = gridDim.x;
    const int wg = blockIdx.x;
    const int swg = (wg & 7) * (nwg >> 3) + (wg >> 3);
    const int bn = swg & ((1 << lg_nbn) - 1);
    const int bm = swg >> lg_nbn;
    const int nt = K >> 6;

    // staging source (pre-swizzled chunk): lane l covers row (wave*8 + l>>3),
    // LDS chunk-slot l&7, which must hold global chunk (l&7)^(l>>3).
    const int lr8 = lane >> 3;
    const int cge = ((lane & 7) ^ lr8) << 3;   // element offset within row
    const bf16_t* Ag  = A   + (size_t)(bm * 256 + wave * 8 + lr8) * K + cge;
    const bf16_t* B1g = B1t + (size_t)(bn * BN  + wave * 8 + lr8) * K + cge;
    const bf16_t* B2g = DUAL ? (B2t + (size_t)(bn * BN + wave * 8 + lr8) * K + cge)
                             : (const bf16_t*)nullptr;

    f32x4 acc1[8][NFR] = {};
    f32x4 acc2[DUAL ? 8 : 1][NFR] = {};

    auto stageA = [&](int u) {   // full A tile of K-tile u (4 loads/thread)
        bf16_t* dst = &lds[(u & 1) * 32768 + wave * 512];
        const bf16_t* src = Ag + ((size_t)u << 6);
        gload16(src,                     dst);
        gload16(src + ((size_t)64  * K), dst + 4096);
        gload16(src + ((size_t)128 * K), dst + 8192);
        gload16(src + ((size_t)192 * K), dst + 12288);
    };
    auto stageB = [&](int u) {   // full B tile(s) of K-tile u (4 loads/thread)
        bf16_t* dst = &lds[(u & 1) * 32768 + 16384 + wave * 512];
        const bf16_t* src = B1g + ((size_t)u << 6);
        gload16(src,                    dst);
        gload16(src + ((size_t)64 * K), dst + 4096);
        if constexpr (DUAL) {
            bf16_t* dst2 = &lds[(u & 1) * 32768 + 24576 + wave * 512];
            const bf16_t* src2 = B2g + ((size_t)u << 6);
            gload16(src2,                    dst2);
            gload16(src2 + ((size_t)64 * K), dst2 + 4096);
        } else {
            gload16(src + ((size_t)128 * K), dst + 8192);
            gload16(src + ((size_t)192 * K), dst + 12288);
        }
    };
    auto rdA = [&](int p, int m, int ks) {   // m in 0..7
        const int row = wr * 128 + m * 16 + lr16;
        const int c = ks * 4 + lk;
        return *(const bf16x8*)&lds[p * 32768 + row * 64 + (((c ^ row) & 7) << 3)];
    };
    auto rdB = [&](int p, int mat, int n, int ks) {
        const int row = wc * (BN / 4) + n * 16 + lr16;
        const int c = ks * 4 + lk;
        return *(const bf16x8*)&lds[p * 32768 + 16384 + mat * 8192 + row * 64 +
                                    (((c ^ row) & 7) << 3)];
    };

    // fragment register banks (double-buffered across phases)
    bf16x8 aFc[4], aFn[4];
    bf16x8 bF0[NMAT][NFR], bF1[NMAT][NFR];

    // prologue: stage tile 0, drain+sync, preload phase-0 fragments
    stageA(0);
    stageB(0);
    __syncthreads();
#pragma unroll
    for (int m = 0; m < 4; ++m) aFc[m] = rdA(0, m, 0);
#pragma unroll
    for (int mat = 0; mat < NMAT; ++mat)
#pragma unroll
        for (int n = 0; n < NFR; ++n) bF0[mat][n] = rdB(0, mat, n, 0);

    for (int t = 0; t < nt; ++t) {
        const int p = t & 1;
        const bool pre = (t + 1 < nt);

        // ---- PH0: compute (mh0, ks0); load (mh1,ks0) + B(ks1); stage A(t+1)
#pragma unroll
        for (int m = 0; m < 4; ++m) aFn[m] = rdA(p, 4 + m, 0);
#pragma unroll
        for (int mat = 0; mat < NMAT; ++mat)
#pragma unroll
            for (int n = 0; n < NFR; ++n) bF1[mat][n] = rdB(p, mat, n, 1);
        if (pre) stageA(t + 1);
#pragma unroll
        for (int m = 0; m < 4; ++m)
#pragma unroll
            for (int n = 0; n < NFR; ++n) {
                acc1[m][n] = MFMA16(aFc[m], bF0[0][n], acc1[m][n]);
                if constexpr (DUAL) acc2[m][n] = MFMA16(aFc[m], bF0[1][n], acc2[m][n]);
            }

        // ---- PH1: compute (mh1, ks0); load (mh0, ks1); stage B(t+1)
#pragma unroll
        for (int m = 0; m < 4; ++m) aFc[m] = rdA(p, m, 1);
        if (pre) stageB(t + 1);
#pragma unroll
        for (int m = 0; m < 4; ++m)
#pragma unroll
            for (int n = 0; n < NFR; ++n) {
                acc1[4 + m][n] = MFMA16(aFn[m], bF0[0][n], acc1[4 + m][n]);
                if constexpr (DUAL) acc2[4 + m][n] = MFMA16(aFn[m], bF0[1][n], acc2[4 + m][n]);
            }

        // ---- PH2: compute (mh0, ks1); load (mh1, ks1)
#pragma unroll
        for (int m = 0; m < 4; ++m) aFn[m] = rdA(p, 4 + m, 1);
#pragma unroll
        for (int m = 0; m < 4; ++m)
#pragma unroll
            for (int n = 0; n < NFR; ++n) {
                acc1[m][n] = MFMA16(aFc[m], bF1[0][n], acc1[m][n]);
                if constexpr (DUAL) acc2[m][n] = MFMA16(aFc[m], bF1[1][n], acc2[m][n]);
            }

        // ---- PH3: compute (mh1, ks1)
#pragma unroll
        for (int m = 0; m < 4; ++m)
#pragma unroll
            for (int n = 0; n < NFR; ++n) {
                acc1[4 + m][n] = MFMA16(aFn[m], bF1[0][n], acc1[4 + m][n]);
                if constexpr (DUAL) acc2[4 + m][n] = MFMA16(aFn[m], bF1[1][n], acc2[4 + m][n]);
            }

        // ---- tile boundary: staging of t+1 drained (vmcnt0) + all waves'
        //      reads of buf p done -> safe to read p^1 and overwrite p next.
        __syncthreads();
        if (pre) {
            const int q = p ^ 1;
#pragma unroll
            for (int m = 0; m < 4; ++m) aFc[m] = rdA(q, m, 0);
#pragma unroll
            for (int mat = 0; mat < NMAT; ++mat)
#pragma unroll
                for (int n = 0; n < NFR; ++n) bF0[mat][n] = rdB(q, mat, n, 0);
        }
    }

    // ---- epilogue ----
    const int rowBase = bm * 256 + wr * 128;
    const int colBase = bn * BN + wc * (BN / 4);
#pragma unroll
    for (int n = 0; n < NFR; ++n) {
        const int col = colBase + n * 16 + lr16;
        float b1v = 0.f, b2v = 0.f;
        if constexpr (MODE == 0) { b1v = bias1[col]; b2v = bias2[col]; }
#pragma unroll
        for (int m = 0; m < 8; ++m) {
#pragma unroll
            for (int j = 0; j < 4; ++j) {
                const int row = rowBase + m * 16 + lk * 4 + j;
                const size_t idx = (size_t)row * N + col;
                if constexpr (MODE == 0) {
                    const float gv = 1.0f / (1.0f + __expf(-(acc1[m][n][j] + b1v)));
                    const float cv = tanhf(acc2[m][n][j] + b2v);
                    bf16x2 pk;
                    pk[0] = (bf16_t)gv;
                    pk[1] = (bf16_t)cv;
                    GC[idx] = pk;
                } else if constexpr (MODE == 1) {
                    const float a = acc1[m][n][j];
                    const float s = a / (1.0f + __expf(-a));
                    Ot[idx] = (bf16_t)(s * acc2[m][n][j]);
                } else {
                    O[idx] += acc1[m][n][j];
                }
            }
        }
    }
}

// ---------------------------------------------------------------------------
// MinGRU scan: h_t = g_t*h_{t-1} + (1-g_t)*c_t, chunked 3-phase.
// gc: [BATCH][SEQ][D_MODEL] packed bf16x2 {g, c}.
// ---------------------------------------------------------------------------
__global__ void scan_phase1(const bf16x2* __restrict__ gc,
                            float* __restrict__ cA, float* __restrict__ cB) {
    const int d = blockIdx.x * 256 + threadIdx.x;
    const int b = blockIdx.y;
    const int cidx = blockIdx.z;
    const int ch = b * D_MODEL + d;
    const size_t base = ((size_t)b * SEQ + (size_t)cidx * CLEN) * D_MODEL + d;
    float A = 1.0f, Bv = 0.0f;
#pragma unroll 8
    for (int t = 0; t < CLEN; ++t) {
        const bf16x2 v = gc[base + (size_t)t * D_MODEL];
        const float gv = (float)v[0], cv = (float)v[1];
        Bv = gv * Bv + (1.0f - gv) * cv;
        A *= gv;
    }
    cA[cidx * NCH + ch] = A;
    cB[cidx * NCH + ch] = Bv;
}

__global__ void scan_phase2(const float* __restrict__ cA,
                            const float* __restrict__ cB,
                            float* __restrict__ hstart) {
    const int ch = blockIdx.x * 256 + threadIdx.x;
    float h = 0.0f;
#pragma unroll 8
    for (int cdx = 0; cdx < NCHUNK; ++cdx) {
        hstart[cdx * NCH + ch] = h;
        h = cA[cdx * NCH + ch] * h + cB[cdx * NCH + ch];
    }
}

// phase3 fused with RMSNorm-2: writes x1 = x + h (fp32, d_out) and
// f_in = rmsnorm(x1, n2w) (bf16). Block = (chunk, batch), 256 thr, 4 ch each.
__global__ __launch_bounds__(256)
void scan_phase3_norm(const bf16x2* __restrict__ gc,
                      const float* __restrict__ hstart,
                      const float* __restrict__ x,
                      const float* __restrict__ n2w,
                      float* __restrict__ x1out, bf16_t* __restrict__ f_in) {
    const int tid = threadIdx.x;
    const int cidx = blockIdx.x;
    const int b = blockIdx.y;
    const int d0 = tid * 4;
    const float4 h4 = *(const float4*)&hstart[cidx * NCH + b * D_MODEL + d0];
    float h0 = h4.x, h1 = h4.y, h2 = h4.z, h3 = h4.w;
    const float4 w4 = *(const float4*)&n2w[d0];
    __shared__ float red[2][4];
    const size_t rowBase = (size_t)b * SEQ + (size_t)cidx * CLEN;
    for (int tt = 0; tt < CLEN; ++tt) {
        const size_t roff = (rowBase + tt) * D_MODEL + d0;
        const bf16x8 gv = *(const bf16x8*)&gc[roff];   // 4 {g,c} pairs
        const float4 xv = *(const float4*)&x[roff];
        float g, c, v0, v1, v2, v3;
        g = (float)gv[0]; c = (float)gv[1]; h0 = g * h0 + (1.f - g) * c; v0 = xv.x + h0;
        g = (float)gv[2]; c = (float)gv[3]; h1 = g * h1 + (1.f - g) * c; v1 = xv.y + h1;
        g = (float)gv[4]; c = (float)gv[5]; h2 = g * h2 + (1.f - g) * c; v2 = xv.z + h2;
        g = (float)gv[6]; c = (float)gv[7]; h3 = g * h3 + (1.f - g) * c; v3 = xv.w + h3;
        float ss = v0 * v0 + v1 * v1 + v2 * v2 + v3 * v3;
#pragma unroll
        for (int o = 1; o < 64; o <<= 1) ss += __shfl_xor(ss, o);
        const int pb = tt & 1;
        if ((tid & 63) == 0) red[pb][tid >> 6] = ss;
        __syncthreads();
        const float tot = red[pb][0] + red[pb][1] + red[pb][2] + red[pb][3];
        const float scale = rsqrtf(tot * (1.0f / D_MODEL) + 1e-6f);
        float4 ov;
        ov.x = v0; ov.y = v1; ov.z = v2; ov.w = v3;
        *(float4*)&x1out[roff] = ov;
        bf16x4 o4;
        o4[0] = (bf16_t)(v0 * scale * w4.x);
        o4[1] = (bf16_t)(v1 * scale * w4.y);
        o4[2] = (bf16_t)(v2 * scale * w4.z);
        o4[3] = (bf16_t)(v3 * scale * w4.w);
        *(bf16x4*)&f_in[roff] = o4;
    }
}

// ---------------------------------------------------------------------------
extern "C" void kernel_launch(void* const* d_in, const int* in_sizes, int n_in,
                              void* d_out, int out_size, void* d_ws,
                              size_t ws_size, hipStream_t stream) {
    const float* x   = (const float*)d_in[0];
    const float* Wg  = (const float*)d_in[1];
    const float* bg  = (const float*)d_in[2];
    const float* Wc  = (const float*)d_in[3];
    const float* bc  = (const float*)d_in[4];
    const float* n1w = (const float*)d_in[5];
    const float* n2w = (const float*)d_in[6];
    const float* W1  = (const float*)d_in[7];
    const float* W3  = (const float*)d_in[8];
    const float* W2  = (const float*)d_in[9];
    float* out = (float*)d_out;

    // Workspace layout (191 MB total; tbuf overlaps h_in+gcbuf+pad, all of
    // which are dead by the time the FFN dual GEMM writes tbuf):
    char* p = (char*)d_ws;
    bf16_t* tbuf  = (bf16_t*)p;                        // 128 MB [0,128)
    bf16_t* h_in  = (bf16_t*)p;  p += (size_t)NTOK * D_MODEL * 2;   // 32 MB
    bf16x2* gcbuf = (bf16x2*)p;  p += (size_t)NTOK * D_MODEL * 4;   // 64 MB
    p += (size_t)32 << 20;                             // pad (tail of tbuf)
    bf16_t* f_in  = (bf16_t*)p;  p += (size_t)NTOK * D_MODEL * 2;   // 32 MB
    bf16_t* Wg_t  = (bf16_t*)p;  p += (size_t)D_MODEL * D_MODEL * 2;
    bf16_t* Wc_t  = (bf16_t*)p;  p += (size_t)D_MODEL * D_MODEL * 2;
    bf16_t* W1_t  = (bf16_t*)p;  p += (size_t)DFF * D_MODEL * 2;
    bf16_t* W3_t  = (bf16_t*)p;  p += (size_t)DFF * D_MODEL * 2;
    bf16_t* W2_t  = (bf16_t*)p;  p += (size_t)D_MODEL * DFF * 2;
    float* cA     = (float*)p;   p += (size_t)NCHUNK * NCH * 4;
    float* cB     = (float*)p;   p += (size_t)NCHUNK * NCH * 4;
    float* hstart = (float*)p;   p += (size_t)NCHUNK * NCH * 4;

    const dim3 tb(32, 8);
    transpose_to_bf16<<<dim3(1024 / 32, 1024 / 32), tb, 0, stream>>>(Wg, Wg_t, 1024, 1024);
    transpose_to_bf16<<<dim3(1024 / 32, 1024 / 32), tb, 0, stream>>>(Wc, Wc_t, 1024, 1024);
    transpose_to_bf16<<<dim3(4096 / 32, 1024 / 32), tb, 0, stream>>>(W1, W1_t, 1024, 4096);
    transpose_to_bf16<<<dim3(4096 / 32, 1024 / 32), tb, 0, stream>>>(W3, W3_t, 1024, 4096);
    transpose_to_bf16<<<dim3(1024 / 32, 4096 / 32), tb, 0, stream>>>(W2, W2_t, 4096, 1024);

    // 1) h_in = rmsnorm(x, n1_w)  (bf16)
    rmsnorm_kernel<<<NTOK, 256, 0, stream>>>(x, n1w, h_in);

    // 2) gc = {sigmoid(h_in@Wg+bg), tanh(h_in@Wc+bc)} packed bf16x2
    //    grid = (M/256)*(N/128) = 64*8 = 512 blocks, lg_nbn = 3
    gemm8p<0><<<512, 512, 0, stream>>>(h_in, Wg_t, Wc_t, bg, bc, gcbuf,
                                       nullptr, nullptr, D_MODEL, D_MODEL, 3);

    // 3) chunked scan; phase3 writes x1 = x + h into d_out AND
    //    f_in = rmsnorm(x1, n2w)  (fused)
    scan_phase1<<<dim3(D_MODEL / 256, BATCH, NCHUNK), 256, 0, stream>>>(gcbuf, cA, cB);
    scan_phase2<<<NCH / 256, 256, 0, stream>>>(cA, cB, hstart);
    scan_phase3_norm<<<dim3(NCHUNK, BATCH), 256, 0, stream>>>(gcbuf, hstart, x,
                                                              n2w, out, f_in);

    // 5) t = silu(f_in@W1) * (f_in@W3)  (bf16)
    //    grid = 64 * (4096/128=32) = 2048 blocks, lg_nbn = 5
    gemm8p<1><<<2048, 512, 0, stream>>>(f_in, W1_t, W3_t, nullptr, nullptr,
                                        nullptr, tbuf, nullptr, DFF, D_MODEL, 5);

    // 6) out = x1 + t@W2  (in-place on d_out)
    //    grid = 64 * (1024/256=4) = 256 blocks, lg_nbn = 2
    gemm8p<2><<<256, 512, 0, stream>>>(tbuf, W2_t, nullptr, nullptr, nullptr,
                                       nullptr, nullptr, out, D_MODEL, DFF, 2);
}

// Round 5
// 761.826 us; speedup vs baseline: 1.0469x; 1.0469x over previous
//
#include <hip/hip_runtime.h>
#include <hip/hip_bf16.h>
#include <math.h>

typedef __bf16 bf16_t;
typedef bf16_t bf16x8 __attribute__((ext_vector_type(8)));
typedef bf16_t bf16x4 __attribute__((ext_vector_type(4)));
typedef bf16_t bf16x2 __attribute__((ext_vector_type(2)));
typedef float f32x4 __attribute__((ext_vector_type(4)));

#define D_MODEL 1024
#define SEQ     4096
#define BATCH   4
#define NTOK    16384   // BATCH*SEQ
#define DFF     4096
#define CLEN    64      // scan chunk length
#define NCHUNK  64      // chunks per sequence (CLEN*NCHUNK == SEQ)
#define NCH     4096    // channels = BATCH*D_MODEL

// async global->LDS, 16B per lane; LDS dest is wave-uniform base + lane*16
__device__ __forceinline__ void gload16(const bf16_t* g, bf16_t* l) {
    __builtin_amdgcn_global_load_lds(
        (const __attribute__((address_space(1))) void*)g,
        (__attribute__((address_space(3))) void*)l, 16, 0, 0);
}

// ---------------------------------------------------------------------------
// Transpose fp32 [R][C] -> bf16 [C][R]
// ---------------------------------------------------------------------------
__global__ void transpose_to_bf16(const float* __restrict__ W,
                                  bf16_t* __restrict__ Wt, int R, int C) {
    __shared__ float tile[32][33];
    const int c0 = blockIdx.x * 32, r0 = blockIdx.y * 32;
    const int tx = threadIdx.x, ty = threadIdx.y;
#pragma unroll
    for (int j = 0; j < 32; j += 8)
        tile[ty + j][tx] = W[(size_t)(r0 + ty + j) * C + c0 + tx];
    __syncthreads();
#pragma unroll
    for (int j = 0; j < 32; j += 8)
        Wt[(size_t)(c0 + ty + j) * R + r0 + tx] = (bf16_t)tile[tx][ty + j];
}

// ---------------------------------------------------------------------------
// RMSNorm: fp32 [rows][1024] -> bf16 [rows][1024]   (block = 256 thr per row)
// ---------------------------------------------------------------------------
__global__ void rmsnorm_kernel(const float* __restrict__ x,
                               const float* __restrict__ w,
                               bf16_t* __restrict__ out) {
    const int row = blockIdx.x;
    const int tid = threadIdx.x;
    const float4 v = ((const float4*)(x + (size_t)row * D_MODEL))[tid];
    float ss = v.x * v.x + v.y * v.y + v.z * v.z + v.w * v.w;
#pragma unroll
    for (int o = 1; o < 64; o <<= 1) ss += __shfl_xor(ss, o);
    __shared__ float red[4];
    if ((tid & 63) == 0) red[tid >> 6] = ss;
    __syncthreads();
    const float tot = red[0] + red[1] + red[2] + red[3];
    const float scale = rsqrtf(tot * (1.0f / D_MODEL) + 1e-6f);
    const float4 wv = ((const float4*)w)[tid];
    bf16x4 o4;
    o4[0] = (bf16_t)(v.x * scale * wv.x);
    o4[1] = (bf16_t)(v.y * scale * wv.y);
    o4[2] = (bf16_t)(v.z * scale * wv.z);
    o4[3] = (bf16_t)(v.w * scale * wv.w);
    ((bf16x4*)(out + (size_t)row * D_MODEL))[tid] = o4;
}

// ---------------------------------------------------------------------------
// 8-phase 256-row GEMM with COUNTED vmcnt pipeline (m201/T3+T4+T5).
// BM=256, BK=64, 512 threads = 8 waves (2M x 4N), double-buffered LDS.
// Staging schedule: A(t+1) at P3 of tile t-1; B(t+1) at P0 of tile t;
// A(t+2) at P3 of tile t (after all-waves-reads-retired barrier).
// Tile boundary waits vmcnt(4) (A(t+2) stays in flight), never 0 in steady
// state. Per-phase: reads | barrier | lgkm0 | sched_barrier | setprio(1) |
// MFMA cluster | setprio(0) | barrier.
//   MODE 0: dual-B BN=128, GC = {sigmoid(A@B1+b1), tanh(A@B2+b2)} bf16x2
//   MODE 1: dual-B BN=128, Ot = silu(A@B1) * (A@B2)   (bf16)
//   MODE 2: single-B BN=256, O += A@B                  (fp32, in-place)
// A: bf16 [M][K]; B*t: bf16 [N][K]. K % 64 == 0 and K >= 128, grid % 8 == 0.
// Swizzle: 16B chunk c of row r at slot c^(r&7); staged via pre-swizzled
// per-lane GLOBAL address, linear LDS dest (global_load_lds constraint).
// ---------------------------------------------------------------------------
#define MFMA16(a, b, c) __builtin_amdgcn_mfma_f32_16x16x32_bf16((a), (b), (c), 0, 0, 0)

template <int MODE>
__global__ __launch_bounds__(512, 2)
void gemm8p(const bf16_t* __restrict__ A, const bf16_t* __restrict__ B1t,
            const bf16_t* __restrict__ B2t, const float* __restrict__ bias1,
            const float* __restrict__ bias2, bf16x2* __restrict__ GC,
            bf16_t* __restrict__ Ot, float* __restrict__ O,
            int N, int K, int lg_nbn) {
    constexpr bool DUAL = (MODE != 2);
    constexpr int BN = DUAL ? 128 : 256;
    constexpr int NFR = DUAL ? 2 : 4;     // n-fragments per wave
    constexpr int NMAT = DUAL ? 2 : 1;
    __shared__ bf16_t lds[65536];         // 128 KiB

    const int tid = threadIdx.x;
    const int lane = tid & 63;
    const int wave = tid >> 6;            // 0..7
    const int wr = wave >> 2, wc = wave & 3;
    const int lr16 = lane & 15, lk = lane >> 4;

    // XCD-bijective block swizzle (gridDim.x % 8 == 0 for all our launches)
    const int nwg = gridDim.x;
    const int wg = blockIdx.x;
    const int swg = (wg & 7) * (nwg >> 3) + (wg >> 3);
    const int bn = swg & ((1 << lg_nbn) - 1);
    const int bm = swg >> lg_nbn;
    const int nt = K >> 6;

    // staging source (pre-swizzled chunk): lane l covers row (wave*8 + l>>3),
    // LDS chunk-slot l&7, which must hold global chunk (l&7)^(l>>3).
    const int lr8 = lane >> 3;
    const int cge = ((lane & 7) ^ lr8) << 3;   // element offset within row
    const bf16_t* Ag  = A   + (size_t)(bm * 256 + wave * 8 + lr8) * K + cge;
    const bf16_t* B1g = B1t + (size_t)(bn * BN  + wave * 8 + lr8) * K + cge;
    const bf16_t* B2g = DUAL ? (B2t + (size_t)(bn * BN + wave * 8 + lr8) * K + cge)
                             : (const bf16_t*)nullptr;

    f32x4 acc1[8][NFR] = {};
    f32x4 acc2[DUAL ? 8 : 1][NFR] = {};

    auto stageA = [&](int u) {   // full A tile of K-tile u (4 loads/thread)
        bf16_t* dst = &lds[(u & 1) * 32768 + wave * 512];
        const bf16_t* src = Ag + ((size_t)u << 6);
        gload16(src,                     dst);
        gload16(src + ((size_t)64  * K), dst + 4096);
        gload16(src + ((size_t)128 * K), dst + 8192);
        gload16(src + ((size_t)192 * K), dst + 12288);
    };
    auto stageB = [&](int u) {   // full B tile(s) of K-tile u (4 loads/thread)
        bf16_t* dst = &lds[(u & 1) * 32768 + 16384 + wave * 512];
        const bf16_t* src = B1g + ((size_t)u << 6);
        gload16(src,                    dst);
        gload16(src + ((size_t)64 * K), dst + 4096);
        if constexpr (DUAL) {
            bf16_t* dst2 = &lds[(u & 1) * 32768 + 24576 + wave * 512];
            const bf16_t* src2 = B2g + ((size_t)u << 6);
            gload16(src2,                    dst2);
            gload16(src2 + ((size_t)64 * K), dst2 + 4096);
        } else {
            gload16(src + ((size_t)128 * K), dst + 8192);
            gload16(src + ((size_t)192 * K), dst + 12288);
        }
    };
    auto rdA = [&](int p, int m, int ks) {   // m in 0..7
        const int row = wr * 128 + m * 16 + lr16;
        const int c = ks * 4 + lk;
        return *(const bf16x8*)&lds[p * 32768 + row * 64 + (((c ^ row) & 7) << 3)];
    };
    auto rdB = [&](int p, int mat, int n, int ks) {
        const int row = wc * (BN / 4) + n * 16 + lr16;
        const int c = ks * 4 + lk;
        return *(const bf16x8*)&lds[p * 32768 + 16384 + mat * 8192 + row * 64 +
                                    (((c ^ row) & 7) << 3)];
    };

    // prologue: stage A(0), B(0), A(1); counted drain (A(1) stays in flight)
    stageA(0);
    stageB(0);
    stageA(1);
    asm volatile("s_waitcnt vmcnt(4)" ::: "memory");
    __builtin_amdgcn_s_barrier();

    for (int t = 0; t < nt; ++t) {
        const int p = t & 1;
        bf16x8 bF[NMAT][NFR];
        bf16x8 aF[4];

        // ---- P0: read B(ks0) + A(mh0,ks0) | stage B(t+1) into buf q ----
#pragma unroll
        for (int mat = 0; mat < NMAT; ++mat)
#pragma unroll
            for (int n = 0; n < NFR; ++n) bF[mat][n] = rdB(p, mat, n, 0);
#pragma unroll
        for (int m = 0; m < 4; ++m) aF[m] = rdA(p, m, 0);
        if (t + 1 < nt) stageB(t + 1);
        __builtin_amdgcn_s_barrier();
        asm volatile("s_waitcnt lgkmcnt(0)" ::: "memory");
        __builtin_amdgcn_sched_barrier(0);
        __builtin_amdgcn_s_setprio(1);
#pragma unroll
        for (int m = 0; m < 4; ++m)
#pragma unroll
            for (int n = 0; n < NFR; ++n) {
                acc1[m][n] = MFMA16(aF[m], bF[0][n], acc1[m][n]);
                if constexpr (DUAL) acc2[m][n] = MFMA16(aF[m], bF[1][n], acc2[m][n]);
            }
        __builtin_amdgcn_s_setprio(0);
        __builtin_amdgcn_s_barrier();

        // ---- P1: read A(mh1,ks0) ----
#pragma unroll
        for (int m = 0; m < 4; ++m) aF[m] = rdA(p, 4 + m, 0);
        __builtin_amdgcn_s_barrier();
        asm volatile("s_waitcnt lgkmcnt(0)" ::: "memory");
        __builtin_amdgcn_sched_barrier(0);
        __builtin_amdgcn_s_setprio(1);
#pragma unroll
        for (int m = 0; m < 4; ++m)
#pragma unroll
            for (int n = 0; n < NFR; ++n) {
                acc1[4 + m][n] = MFMA16(aF[m], bF[0][n], acc1[4 + m][n]);
                if constexpr (DUAL) acc2[4 + m][n] = MFMA16(aF[m], bF[1][n], acc2[4 + m][n]);
            }
        __builtin_amdgcn_s_setprio(0);
        __builtin_amdgcn_s_barrier();

        // ---- P2: read B(ks1) + A(mh0,ks1) ----
#pragma unroll
        for (int mat = 0; mat < NMAT; ++mat)
#pragma unroll
            for (int n = 0; n < NFR; ++n) bF[mat][n] = rdB(p, mat, n, 1);
#pragma unroll
        for (int m = 0; m < 4; ++m) aF[m] = rdA(p, m, 1);
        __builtin_amdgcn_s_barrier();
        asm volatile("s_waitcnt lgkmcnt(0)" ::: "memory");
        __builtin_amdgcn_sched_barrier(0);
        __builtin_amdgcn_s_setprio(1);
#pragma unroll
        for (int m = 0; m < 4; ++m)
#pragma unroll
            for (int n = 0; n < NFR; ++n) {
                acc1[m][n] = MFMA16(aF[m], bF[0][n], acc1[m][n]);
                if constexpr (DUAL) acc2[m][n] = MFMA16(aF[m], bF[1][n], acc2[m][n]);
            }
        __builtin_amdgcn_s_setprio(0);
        __builtin_amdgcn_s_barrier();

        // ---- P3: read A(mh1,ks1); all-waves-retired barrier; stage A(t+2)
        //      into buf p; MFMA; COUNTED vmcnt; barrier ----
#pragma unroll
        for (int m = 0; m < 4; ++m) aF[m] = rdA(p, 4 + m, 1);
        asm volatile("s_waitcnt lgkmcnt(0)" ::: "memory");
        __builtin_amdgcn_s_barrier();          // all waves done reading buf p
        if (t + 2 < nt) stageA(t + 2);
        __builtin_amdgcn_sched_barrier(0);
        __builtin_amdgcn_s_setprio(1);
#pragma unroll
        for (int m = 0; m < 4; ++m)
#pragma unroll
            for (int n = 0; n < NFR; ++n) {
                acc1[4 + m][n] = MFMA16(aF[m], bF[0][n], acc1[4 + m][n]);
                if constexpr (DUAL) acc2[4 + m][n] = MFMA16(aF[m], bF[1][n], acc2[4 + m][n]);
            }
        __builtin_amdgcn_s_setprio(0);
        __builtin_amdgcn_sched_barrier(0);
        if (t + 2 < nt) {
            asm volatile("s_waitcnt vmcnt(4)" ::: "memory");  // A(t+1),B(t+1) landed
        } else {
            asm volatile("s_waitcnt vmcnt(0)" ::: "memory");  // tail drain
        }
        __builtin_amdgcn_s_barrier();
    }

    // ---- epilogue ----
    const int rowBase = bm * 256 + wr * 128;
    const int colBase = bn * BN + wc * (BN / 4);
#pragma unroll
    for (int n = 0; n < NFR; ++n) {
        const int col = colBase + n * 16 + lr16;
        float b1v = 0.f, b2v = 0.f;
        if constexpr (MODE == 0) { b1v = bias1[col]; b2v = bias2[col]; }
#pragma unroll
        for (int m = 0; m < 8; ++m) {
#pragma unroll
            for (int j = 0; j < 4; ++j) {
                const int row = rowBase + m * 16 + lk * 4 + j;
                const size_t idx = (size_t)row * N + col;
                if constexpr (MODE == 0) {
                    const float gv = 1.0f / (1.0f + __expf(-(acc1[m][n][j] + b1v)));
                    const float cv = tanhf(acc2[m][n][j] + b2v);
                    bf16x2 pk;
                    pk[0] = (bf16_t)gv;
                    pk[1] = (bf16_t)cv;
                    GC[idx] = pk;
                } else if constexpr (MODE == 1) {
                    const float a = acc1[m][n][j];
                    const float s = a / (1.0f + __expf(-a));
                    Ot[idx] = (bf16_t)(s * acc2[m][n][j]);
                } else {
                    O[idx] += acc1[m][n][j];
                }
            }
        }
    }
}

// ---------------------------------------------------------------------------
// MinGRU scan: h_t = g_t*h_{t-1} + (1-g_t)*c_t, chunked 3-phase.
// gc: [BATCH][SEQ][D_MODEL] packed bf16x2 {g, c}.
// ---------------------------------------------------------------------------
__global__ void scan_phase1(const bf16x2* __restrict__ gc,
                            float* __restrict__ cA, float* __restrict__ cB) {
    const int d = blockIdx.x * 256 + threadIdx.x;
    const int b = blockIdx.y;
    const int cidx = blockIdx.z;
    const int ch = b * D_MODEL + d;
    const size_t base = ((size_t)b * SEQ + (size_t)cidx * CLEN) * D_MODEL + d;
    float A = 1.0f, Bv = 0.0f;
#pragma unroll 8
    for (int t = 0; t < CLEN; ++t) {
        const bf16x2 v = gc[base + (size_t)t * D_MODEL];
        const float gv = (float)v[0], cv = (float)v[1];
        Bv = gv * Bv + (1.0f - gv) * cv;
        A *= gv;
    }
    cA[cidx * NCH + ch] = A;
    cB[cidx * NCH + ch] = Bv;
}

__global__ void scan_phase2(const float* __restrict__ cA,
                            const float* __restrict__ cB,
                            float* __restrict__ hstart) {
    const int ch = blockIdx.x * 256 + threadIdx.x;
    float h = 0.0f;
#pragma unroll 8
    for (int cdx = 0; cdx < NCHUNK; ++cdx) {
        hstart[cdx * NCH + ch] = h;
        h = cA[cdx * NCH + ch] * h + cB[cdx * NCH + ch];
    }
}

__global__ void scan_phase3(const bf16x2* __restrict__ gc,
                            const float* __restrict__ hstart,
                            const float* __restrict__ x,
                            float* __restrict__ x1) {
    const int d = blockIdx.x * 256 + threadIdx.x;
    const int b = blockIdx.y;
    const int cidx = blockIdx.z;
    const int ch = b * D_MODEL + d;
    const size_t base = ((size_t)b * SEQ + (size_t)cidx * CLEN) * D_MODEL + d;
    float h = hstart[cidx * NCH + ch];
#pragma unroll 8
    for (int t = 0; t < CLEN; ++t) {
        const size_t off = base + (size_t)t * D_MODEL;
        const bf16x2 v = gc[off];
        const float gv = (float)v[0], cv = (float)v[1];
        h = gv * h + (1.0f - gv) * cv;
        x1[off] = x[off] + h;
    }
}

// ---------------------------------------------------------------------------
extern "C" void kernel_launch(void* const* d_in, const int* in_sizes, int n_in,
                              void* d_out, int out_size, void* d_ws,
                              size_t ws_size, hipStream_t stream) {
    const float* x   = (const float*)d_in[0];
    const float* Wg  = (const float*)d_in[1];
    const float* bg  = (const float*)d_in[2];
    const float* Wc  = (const float*)d_in[3];
    const float* bc  = (const float*)d_in[4];
    const float* n1w = (const float*)d_in[5];
    const float* n2w = (const float*)d_in[6];
    const float* W1  = (const float*)d_in[7];
    const float* W3  = (const float*)d_in[8];
    const float* W2  = (const float*)d_in[9];
    float* out = (float*)d_out;

    // Workspace layout (191 MB total; tbuf overlaps h_in+gcbuf+pad, all of
    // which are dead by the time the FFN dual GEMM writes tbuf):
    char* p = (char*)d_ws;
    bf16_t* tbuf  = (bf16_t*)p;                        // 128 MB [0,128)
    bf16_t* h_in  = (bf16_t*)p;  p += (size_t)NTOK * D_MODEL * 2;   // 32 MB
    bf16x2* gcbuf = (bf16x2*)p;  p += (size_t)NTOK * D_MODEL * 4;   // 64 MB
    p += (size_t)32 << 20;                             // pad (tail of tbuf)
    bf16_t* f_in  = (bf16_t*)p;  p += (size_t)NTOK * D_MODEL * 2;   // 32 MB
    bf16_t* Wg_t  = (bf16_t*)p;  p += (size_t)D_MODEL * D_MODEL * 2;
    bf16_t* Wc_t  = (bf16_t*)p;  p += (size_t)D_MODEL * D_MODEL * 2;
    bf16_t* W1_t  = (bf16_t*)p;  p += (size_t)DFF * D_MODEL * 2;
    bf16_t* W3_t  = (bf16_t*)p;  p += (size_t)DFF * D_MODEL * 2;
    bf16_t* W2_t  = (bf16_t*)p;  p += (size_t)D_MODEL * DFF * 2;
    float* cA     = (float*)p;   p += (size_t)NCHUNK * NCH * 4;
    float* cB     = (float*)p;   p += (size_t)NCHUNK * NCH * 4;
    float* hstart = (float*)p;   p += (size_t)NCHUNK * NCH * 4;

    const dim3 tb(32, 8);
    transpose_to_bf16<<<dim3(1024 / 32, 1024 / 32), tb, 0, stream>>>(Wg, Wg_t, 1024, 1024);
    transpose_to_bf16<<<dim3(1024 / 32, 1024 / 32), tb, 0, stream>>>(Wc, Wc_t, 1024, 1024);
    transpose_to_bf16<<<dim3(4096 / 32, 1024 / 32), tb, 0, stream>>>(W1, W1_t, 1024, 4096);
    transpose_to_bf16<<<dim3(4096 / 32, 1024 / 32), tb, 0, stream>>>(W3, W3_t, 1024, 4096);
    transpose_to_bf16<<<dim3(1024 / 32, 4096 / 32), tb, 0, stream>>>(W2, W2_t, 4096, 1024);

    // 1) h_in = rmsnorm(x, n1_w)  (bf16)
    rmsnorm_kernel<<<NTOK, 256, 0, stream>>>(x, n1w, h_in);

    // 2) gc = {sigmoid(h_in@Wg+bg), tanh(h_in@Wc+bc)} packed bf16x2
    //    grid = (M/256)*(N/128) = 64*8 = 512 blocks, lg_nbn = 3
    gemm8p<0><<<512, 512, 0, stream>>>(h_in, Wg_t, Wc_t, bg, bc, gcbuf,
                                       nullptr, nullptr, D_MODEL, D_MODEL, 3);

    // 3) chunked scan; phase3 writes x1 = x + h into d_out
    scan_phase1<<<dim3(D_MODEL / 256, BATCH, NCHUNK), 256, 0, stream>>>(gcbuf, cA, cB);
    scan_phase2<<<NCH / 256, 256, 0, stream>>>(cA, cB, hstart);
    scan_phase3<<<dim3(D_MODEL / 256, BATCH, NCHUNK), 256, 0, stream>>>(gcbuf, hstart, x, out);

    // 4) f_in = rmsnorm(x1, n2_w)
    rmsnorm_kernel<<<NTOK, 256, 0, stream>>>(out, n2w, f_in);

    // 5) t = silu(f_in@W1) * (f_in@W3)  (bf16)
    //    grid = 64 * (4096/128=32) = 2048 blocks, lg_nbn = 5
    gemm8p<1><<<2048, 512, 0, stream>>>(f_in, W1_t, W3_t, nullptr, nullptr,
                                        nullptr, tbuf, nullptr, DFF, D_MODEL, 5);

    // 6) out = x1 + t@W2  (in-place on d_out)
    //    grid = 64 * (1024/256=4) = 256 blocks, lg_nbn = 2
    gemm8p<2><<<256, 512, 0, stream>>>(tbuf, W2_t, nullptr, nullptr, nullptr,
                                       nullptr, nullptr, out, D_MODEL, DFF, 2);
}